// Round 2
// baseline (122.737 us; speedup 1.0000x reference)
//
#include <hip/hip_runtime.h>
#include <math.h>

#define NFREQ 10
#define INV2PI 0.15915494309189535f
#define TPB 256

typedef float v2f __attribute__((ext_vector_type(2)));

// Folded coefficients in static device memory (d_ws untouched).
// Per freq i: g_fr[i] = freq/2pi; g_P[i] = (phase_x, phase_y) revs;
// g_R[i] = (amp_x, amp_y).  A sin(th)+B cos(th) = R sin(th+phi).
__device__ float g_fr[NFREQ];
__device__ v2f   g_P[NFREQ];
__device__ v2f   g_R[NFREQ];

__device__ __forceinline__ v2f mkv2(float a, float b) { v2f r; r.x = a; r.y = b; return r; }

__global__ void coeff_kernel(const float* __restrict__ freqs,
                             const float* __restrict__ weight) {
    int i = threadIdx.x;
    if (i < NFREQ) {
        g_fr[i] = freqs[2 * i] * INV2PI;
        float A0 = weight[2 * i],             B0 = weight[2 * i + 1];
        float A1 = weight[2 * NFREQ + 2 * i], B1 = weight[2 * NFREQ + 2 * i + 1];
        g_R[i] = mkv2(sqrtf(A0 * A0 + B0 * B0), sqrtf(A1 * A1 + B1 * B1));
        g_P[i] = mkv2(atan2f(B0, A0) * INV2PI, atan2f(B1, A1) * INV2PI);
    }
}

__device__ __forceinline__ float frag_eval(v2f c, const float* __restrict__ fr,
                                           const v2f* __restrict__ P,
                                           const v2f* __restrict__ R) {
    v2f acc = mkv2(0.f, 0.f);
#pragma unroll
    for (int i = 0; i < NFREQ; ++i) {
        v2f th = c * fr[i] + P[i];
        v2f s;
        s.x = __builtin_amdgcn_sinf(th.x);
        s.y = __builtin_amdgcn_sinf(th.y);
        acc += R[i] * s;
    }
    return acc.x + acc.y;
}

// ---------------------------------------------------------------------------
// Single-writer, atomic-free scan. Each wave handles 128 fragments
// [b, b+128). Uniform peeks pk=ix[b-1], nk=ix[b+128], lk=ix[e-1] tell it
// which boundary runs it owns. Ownership rule: the wave containing a run's
// LAST fragment finalizes it with a plain store out[K] = bias + sum; the
// finalizing wave re-evaluates any fragments of that run that live in
// earlier waves (serial walk-back on lane 0, mean ~1.3 frags). Gap keys
// (no fragments) are written bias-only by the head lane of the following
// run. Every out[] element has exactly one writer computing in a fixed
// order -> deterministic, no zero-init pass, no finish pass, no atomics.
//
// Segmented suffix scan keyed on each lane's FIRST key (sorted ix => if
// ka(l+d)==ka(l) every fragment in between has that key, so the doubling
// recursion is exact). Impure lanes own the head of their SECOND key's
// run: total = sb + v(l+1) if lane l+1 continues it.
// ---------------------------------------------------------------------------
__global__ __launch_bounds__(TPB) void scan_kernel(
        const float* __restrict__ coords,   // [F,2]
        const int*   __restrict__ ix,       // [F], sorted
        const float* __restrict__ bias,     // [gene_n]
        const int*   __restrict__ gix,      // [gene_n]
        float* __restrict__ out,            // [total]
        int gene_n, int total, int F) {
    float fr[NFREQ]; v2f P[NFREQ], R[NFREQ];
#pragma unroll
    for (int i = 0; i < NFREQ; ++i) {       // uniform -> scalar loads
        fr[i] = g_fr[i]; P[i] = g_P[i]; R[i] = g_R[i];
    }

    const int w    = (blockIdx.x * TPB + threadIdx.x) >> 6; // global wave id
    const int lane = threadIdx.x & 63;
    const int b    = w << 7;                // 128 fragments per wave
    if (b >= F) return;
    const int e  = min(b + 128, F);
    const int pk = (b > 0) ? ix[b - 1] : -1;          // uniform loads
    const int nk = (e < F) ? ix[e] : 0x7fffffff;
    const int lk = ix[e - 1];

    const int f0 = b + 2 * lane;
    int   ka = -2, kb = -2;
    float sa = 0.f, sb = 0.f;
    if (f0 + 1 < F) {
        int2   k2 = *(const int2*)(ix + f0);
        float4 c4 = *(const float4*)(coords + 2 * f0);
        ka = k2.x; kb = k2.y;
        sa = frag_eval(mkv2(c4.x, c4.y), fr, P, R);
        sb = frag_eval(mkv2(c4.z, c4.w), fr, P, R);
    } else if (f0 < F) {                    // odd tail: treat as pure pair
        ka = kb = ix[f0];
        float2 c2 = *(const float2*)(coords + 2 * f0);
        sa = frag_eval(mkv2(c2.x, c2.y), fr, P, R);
    }

    const bool pure = (ka == kb);
    float v = pure ? (sa + sb) : sa;        // contribution to ka's run
#pragma unroll
    for (int d = 1; d < 64; d <<= 1) {
        float ov = __shfl_down(v, d);
        int   ok = __shfl_down(ka, d);
        if (lane + d < 64 && ok == ka) v += ov;
    }
    const float nv  = __shfl_down(v, 1);    // next lane's scanned leading run
    const int   nkl = __shfl_down(ka, 1);
    const int   pkb = __shfl_up(kb, 1);     // previous lane's LAST key

    // ---- head of this lane's leading run ----
    if (ka >= 0 && (lane == 0 || ka != pkb)) {
        const int Pk = (lane == 0) ? pk : pkb;
        for (int K2 = Pk + 1; K2 < ka; ++K2)            // gap keys: bias only
            out[K2] = bias[gix[K2 % gene_n]];
        if (!(ka == lk && lk == nk)) {                  // run ends in this wave
            float tot = v;
            if (lane == 0 && ka == pk) {                // continues backwards
                for (int j = b - 1; j >= 0 && ix[j] == ka; --j) {
                    float2 c2 = *(const float2*)(coords + 2 * j);
                    tot += frag_eval(mkv2(c2.x, c2.y), fr, P, R);
                }
            }
            out[ka] = bias[gix[ka % gene_n]] + tot;
        }
    }
    // ---- head of the run starting at this lane's second fragment ----
    if (kb >= 0 && kb != ka) {
        for (int K2 = ka + 1; K2 < kb; ++K2)            // gap keys: bias only
            out[K2] = bias[gix[K2 % gene_n]];
        if (!(kb == lk && lk == nk)) {
            float tb = sb + ((lane < 63 && nkl == kb) ? nv : 0.f);
            out[kb] = bias[gix[kb % gene_n]] + tb;
        }
    }
    // ---- keys beyond the last fragment (last wave only) ----
    if (e == F && lane == 0) {
        for (int K2 = lk + 1; K2 < total; ++K2)
            out[K2] = bias[gix[K2 % gene_n]];
    }
}

extern "C" void kernel_launch(void* const* d_in, const int* in_sizes, int n_in,
                              void* d_out, int out_size, void* d_ws, size_t ws_size,
                              hipStream_t stream) {
    const float* coords  = (const float*)d_in[0];
    const int*   ix      = (const int*)d_in[1];
    const int*   gene_ix = (const int*)d_in[4];
    const float* freqs   = (const float*)d_in[5];
    const float* weight  = (const float*)d_in[7];
    const float* bias    = (const float*)d_in[8];
    float* out = (float*)d_out;

    int F      = in_sizes[1];
    int gene_n = in_sizes[4];
    int total  = out_size;

    (void)d_ws; (void)ws_size; (void)n_in;

    hipLaunchKernelGGL(coeff_kernel, dim3(1), dim3(64), 0, stream,
                       freqs, weight);

    int blocks = (F + TPB * 2 - 1) / (TPB * 2);
    hipLaunchKernelGGL(scan_kernel, dim3(blocks), dim3(TPB), 0, stream,
                       coords, ix, bias, gene_ix, out, gene_n, total, F);
}

// Round 3
// 116.204 us; speedup vs baseline: 1.0562x; 1.0562x over previous
//
#include <hip/hip_runtime.h>
#include <math.h>

#define NFREQ 10
#define INV2PI 0.15915494309189535f
#define TPB 256

typedef float v2f __attribute__((ext_vector_type(2)));

// Folded coefficients in static device memory (d_ws untouched).
// Per freq i: g_fr[i] = freq/2pi; g_P[i] = (phase_x, phase_y) revs;
// g_R[i] = (amp_x, amp_y).  A sin(th)+B cos(th) = R sin(th+phi).
__device__ float g_fr[NFREQ];
__device__ v2f   g_P[NFREQ];
__device__ v2f   g_R[NFREQ];

__device__ __forceinline__ v2f mkv2(float a, float b) { v2f r; r.x = a; r.y = b; return r; }

// ---------------------------------------------------------------------------
// fill_kernel: out[K] = bias[gix[K % gene_n]] for ALL K (streaming float4),
// so the scan never touches gap keys, the tail, or the bias indirection.
// Block 0 lanes 0..9 additionally fold the coefficients.
// K % gene_n via exact double reciprocal: K < 2^21, (K+0.5)*inv_g is never
// within 1e-9 of an integer boundary (margin 0.5/gene_n ~ 5e-4).
// ---------------------------------------------------------------------------
__global__ __launch_bounds__(256) void fill_kernel(
        float* __restrict__ out, const float* __restrict__ bias,
        const int* __restrict__ gix, int gene_n, int total, double inv_g,
        const float* __restrict__ freqs, const float* __restrict__ weight) {
    if (blockIdx.x == 0 && threadIdx.x < NFREQ) {
        int i = threadIdx.x;
        g_fr[i] = freqs[2 * i] * INV2PI;
        float A0 = weight[2 * i],             B0 = weight[2 * i + 1];
        float A1 = weight[2 * NFREQ + 2 * i], B1 = weight[2 * NFREQ + 2 * i + 1];
        g_R[i] = mkv2(sqrtf(A0 * A0 + B0 * B0), sqrtf(A1 * A1 + B1 * B1));
        g_P[i] = mkv2(atan2f(B0, A0) * INV2PI, atan2f(B1, A1) * INV2PI);
    }
    int b = (blockIdx.x * 256 + threadIdx.x) * 4;
    if (b >= total) return;
    int q = (int)((b + 0.5) * inv_g);
    int g = b - q * gene_n;
    float v[4];
#pragma unroll
    for (int k = 0; k < 4; ++k) {
        int gg = g + k;
        if (gg >= gene_n) gg -= gene_n;
        v[k] = bias[gix[gg]];
    }
    if (b + 3 < total) {
        *(float4*)(out + b) = make_float4(v[0], v[1], v[2], v[3]);
    } else {
        for (int k = 0; k < 4 && b + k < total; ++k) out[b + k] = v[k];
    }
}

__device__ __forceinline__ float frag_eval(v2f c, const float* __restrict__ fr,
                                           const v2f* __restrict__ P,
                                           const v2f* __restrict__ R) {
    v2f acc = mkv2(0.f, 0.f);
#pragma unroll
    for (int i = 0; i < NFREQ; ++i) {
        v2f th = c * fr[i] + P[i];
        v2f s;
        s.x = __builtin_amdgcn_sinf(th.x);
        s.y = __builtin_amdgcn_sinf(th.y);
        acc += R[i] * s;
    }
    return acc.x + acc.y;
}

// ---------------------------------------------------------------------------
// Single-writer, atomic-free scan over pre-filled out[].
// Wave handles 128 fragments [b,b+128). Ownership: the wave containing a
// run's LAST fragment finalizes it with out[K] += run_sum (bias already
// there from fill_kernel; unique writer per K -> no atomics, deterministic).
// Backward-crossing runs: all 64 lanes jointly re-evaluate up to 64
// backward fragments per chunk (key-match predicate is exact since ix is
// sorted), butterfly-reduce, lane 0 adds. No serial sin chains.
// Segmented suffix scan keyed on each lane's FIRST key; impure lanes own
// the head of their SECOND key's run (total = sb + next lane's scanned v).
// ---------------------------------------------------------------------------
__global__ __launch_bounds__(TPB) void scan_kernel(
        const float* __restrict__ coords,   // [F,2]
        const int*   __restrict__ ix,       // [F], sorted
        float* __restrict__ out,            // [total], pre-filled with bias
        int F) {
    float fr[NFREQ]; v2f P[NFREQ], R[NFREQ];
#pragma unroll
    for (int i = 0; i < NFREQ; ++i) {       // uniform -> scalar loads
        fr[i] = g_fr[i]; P[i] = g_P[i]; R[i] = g_R[i];
    }

    const int w    = (blockIdx.x * TPB + threadIdx.x) >> 6; // global wave id
    const int lane = threadIdx.x & 63;
    const int b    = w << 7;                // 128 fragments per wave
    if (b >= F) return;
    const int e  = min(b + 128, F);
    const int pk = (b > 0) ? ix[b - 1] : -1;          // uniform loads
    const int nk = (e < F) ? ix[e] : 0x7fffffff;
    const int lk = ix[e - 1];

    const int f0 = b + 2 * lane;
    int   ka = -2, kb = -2;
    float sa = 0.f, sb = 0.f;
    if (f0 + 1 < F) {
        int2   k2 = *(const int2*)(ix + f0);
        float4 c4 = *(const float4*)(coords + 2 * f0);
        ka = k2.x; kb = k2.y;
        sa = frag_eval(mkv2(c4.x, c4.y), fr, P, R);
        sb = frag_eval(mkv2(c4.z, c4.w), fr, P, R);
    } else if (f0 < F) {                    // odd tail: treat as pure pair
        ka = kb = ix[f0];
        float2 c2 = *(const float2*)(coords + 2 * f0);
        sa = frag_eval(mkv2(c2.x, c2.y), fr, P, R);
    }

    const bool pure = (ka == kb);
    float v = pure ? (sa + sb) : sa;        // contribution to ka's run
#pragma unroll
    for (int d = 1; d < 64; d <<= 1) {
        float ov = __shfl_down(v, d);
        int   ok = __shfl_down(ka, d);
        if (lane + d < 64 && ok == ka) v += ov;
    }
    const float nv  = __shfl_down(v, 1);    // next lane's scanned leading run
    const int   nkl = __shfl_down(ka, 1);
    const int   pkb = __shfl_up(kb, 1);     // previous lane's LAST key

    // ---- parallel walk-back for the wave's leading run (wave-uniform) ----
    const int  ka0   = __shfl(ka, 0);
    const bool ends0 = !(ka0 == lk && lk == nk);
    if (pk == ka0 && ends0) {               // run continues backwards; we own it
        float wb = 0.f;
        int j = b - 1 - lane;
        for (;;) {
            bool m = (j >= 0) && (ix[j] == ka0);
            if (m) {
                float2 c2 = *(const float2*)(coords + 2 * j);
                wb += frag_eval(mkv2(c2.x, c2.y), fr, P, R);
            }
            if (!__all(m)) break;           // hit run start (or j<0) somewhere
            j -= 64;
        }
#pragma unroll
        for (int d = 1; d < 64; d <<= 1) wb += __shfl_xor(wb, d);
        if (lane == 0) v += wb;
    }

    // ---- head of this lane's leading run ----
    if (ka >= 0 && (lane == 0 || ka != pkb)) {
        if (!(ka == lk && lk == nk))        // run ends in this wave -> we own it
            out[ka] += v;
    }
    // ---- head of the run starting at this lane's second fragment ----
    if (kb >= 0 && kb != ka) {
        if (!(kb == lk && lk == nk)) {
            float tb = sb + ((lane < 63 && nkl == kb) ? nv : 0.f);
            out[kb] += tb;
        }
    }
}

extern "C" void kernel_launch(void* const* d_in, const int* in_sizes, int n_in,
                              void* d_out, int out_size, void* d_ws, size_t ws_size,
                              hipStream_t stream) {
    const float* coords  = (const float*)d_in[0];
    const int*   ix      = (const int*)d_in[1];
    const int*   gene_ix = (const int*)d_in[4];
    const float* freqs   = (const float*)d_in[5];
    const float* weight  = (const float*)d_in[7];
    const float* bias    = (const float*)d_in[8];
    float* out = (float*)d_out;

    int F      = in_sizes[1];
    int gene_n = in_sizes[4];
    int total  = out_size;

    (void)d_ws; (void)ws_size; (void)n_in;

    int fthreads = (total + 3) / 4;
    hipLaunchKernelGGL(fill_kernel, dim3((fthreads + 255) / 256), dim3(256),
                       0, stream, out, bias, gene_ix, gene_n, total,
                       1.0 / (double)gene_n, freqs, weight);

    int blocks = (F + TPB * 2 - 1) / (TPB * 2);
    hipLaunchKernelGGL(scan_kernel, dim3(blocks), dim3(TPB), 0, stream,
                       coords, ix, out, F);
}

// Round 4
// 110.684 us; speedup vs baseline: 1.1089x; 1.0499x over previous
//
#include <hip/hip_runtime.h>
#include <math.h>

#define NFREQ 10
#define INV2PI 0.15915494309189535f
#define TPB 256
#define SCALE_F 1048576.0f             // 2^20 fixed-point scale
#define INV_SCALE 9.5367431640625e-07f // 2^-20

typedef float v2f __attribute__((ext_vector_type(2)));

// Folded coefficients in static device memory (d_ws untouched).
// Per freq i: g_fr[i] = freq/2pi; g_P[i] = (phase_x, phase_y) revs;
// g_R[i] = (amp_x, amp_y).  A sin(th)+B cos(th) = R sin(th+phi); gfx950
// v_sin takes revolutions -> 20 v_sin + ~20 v_pk_fma per fragment pair.
//
// SESSION CONCLUSION (rounds 0-3): the timed iteration is dominated by the
// harness's 256 MiB workspace poison fill (~44 us at 76-80% HBM peak, one
// per iteration) plus reset memsets; four structurally different kernels
// (atomics / single-writer / prefill variants) all land 110.5-122.7 us.
// This file is the measured-best structure (round 1, 110.5 us): int32
// fixed-point atomics -> integer addition is associative -> bit-
// deterministic across graph replays regardless of atomic order.
// Quantization error ~1e-6/bucket; overflow margin ~200x.
__device__ float g_fr[NFREQ];
__device__ v2f   g_P[NFREQ];
__device__ v2f   g_R[NFREQ];

__device__ __forceinline__ v2f mkv2(float a, float b) { v2f r; r.x = a; r.y = b; return r; }

// ---------------------------------------------------------------------------
// init: zero the int32 accumulators (out buffer) AND fold the 50
// coefficients in block 0 (one dispatch for both).
// ---------------------------------------------------------------------------
__global__ __launch_bounds__(256) void init_kernel(int* __restrict__ acc, int total,
                                                   const float* __restrict__ freqs,
                                                   const float* __restrict__ weight) {
    if (blockIdx.x == 0 && threadIdx.x < NFREQ) {
        int i = threadIdx.x;
        g_fr[i] = freqs[2 * i] * INV2PI;
        float A0 = weight[2 * i],             B0 = weight[2 * i + 1];
        float A1 = weight[2 * NFREQ + 2 * i], B1 = weight[2 * NFREQ + 2 * i + 1];
        g_R[i] = mkv2(sqrtf(A0 * A0 + B0 * B0), sqrtf(A1 * A1 + B1 * B1));
        g_P[i] = mkv2(atan2f(B0, A0) * INV2PI, atan2f(B1, A1) * INV2PI);
    }
    int b = (blockIdx.x * blockDim.x + threadIdx.x) * 4;
    if (b + 3 < total) {
        *(int4*)(acc + b) = make_int4(0, 0, 0, 0);
    } else {
        for (int k = 0; k < 4; ++k)
            if (b + k < total) acc[b + k] = 0;
    }
}

// Packed (x,y) evaluation: v2f ops encourage v_pk_fma_f32; 20 sins per
// fragment pair stay scalar (v_sin_f32, input in revolutions).
__device__ __forceinline__ float frag_eval(v2f c, const float* __restrict__ fr,
                                           const v2f* __restrict__ P,
                                           const v2f* __restrict__ R) {
    v2f acc = mkv2(0.f, 0.f);
#pragma unroll
    for (int i = 0; i < NFREQ; ++i) {
        v2f th = c * fr[i] + P[i];
        v2f s;
        s.x = __builtin_amdgcn_sinf(th.x);
        s.y = __builtin_amdgcn_sinf(th.y);
        acc += R[i] * s;
    }
    return acc.x + acc.y;
}

// ---------------------------------------------------------------------------
// Two fragments per thread. Pure pairs (same key) merge locally; the wave
// runs a 6-step segmented suffix scan keyed on each lane's FIRST key
// (sorted ix => if ka(l+d)==ka(l), every fragment in between shares that
// key, so the doubling recursion is exact). Impure lanes own the head of
// their SECOND key's run: total = sb + v(l+1) if lane l+1 continues it.
// Every run-head does one int32 fixed-point atomicAdd; runs crossing wave
// boundaries get one atomic from each wave — order-independent and
// deterministic. No cross-wave walks, no gap/tail logic in the hot loop.
// ---------------------------------------------------------------------------
__global__ __launch_bounds__(TPB) void scan_kernel(
        const float* __restrict__ coords,   // [F,2]
        const int*   __restrict__ ix,       // [F], sorted
        int* __restrict__ acc,              // [total] int32 accumulators (=out)
        int F) {
    float fr[NFREQ]; v2f P[NFREQ], R[NFREQ];
#pragma unroll
    for (int i = 0; i < NFREQ; ++i) {       // uniform -> scalar loads
        fr[i] = g_fr[i]; P[i] = g_P[i]; R[i] = g_R[i];
    }

    const int t    = blockIdx.x * TPB + threadIdx.x;
    const int f0   = 2 * t;                 // F = 4M fits in int
    const int lane = threadIdx.x & 63;

    int   ka = -2, kb = -3;                 // distinct sentinels for tail
    float sa = 0.f, sb = 0.f;
    if (f0 + 1 < F) {
        int2   k2 = *(const int2*)(ix + f0);
        float4 c4 = *(const float4*)(coords + 2 * f0);
        ka = k2.x; kb = k2.y;
        sa = frag_eval(mkv2(c4.x, c4.y), fr, P, R);
        sb = frag_eval(mkv2(c4.z, c4.w), fr, P, R);
    } else if (f0 < F) {                    // odd tail: single fragment
        ka = ix[f0];
        float2 c2 = *(const float2*)(coords + 2 * f0);
        sa = frag_eval(mkv2(c2.x, c2.y), fr, P, R);
    }

    const bool pure = (ka == kb);
    float v = pure ? (sa + sb) : sa;        // contribution to ka's run
#pragma unroll
    for (int d = 1; d < 64; d <<= 1) {
        float ov = __shfl_down(v, d);
        int   ok = __shfl_down(ka, d);
        if (lane + d < 64 && ok == ka) v += ov;
    }

    const float nv  = __shfl_down(v, 1);    // next lane's scanned leading run
    const int   nkl = __shfl_down(ka, 1);
    const int   pkb = __shfl_up(kb, 1);     // previous lane's LAST key

    if (ka >= 0 && (lane == 0 || ka != pkb))
        atomicAdd(acc + ka, __float2int_rn(v * SCALE_F));

    if (kb >= 0 && !pure) {                 // lane owns the head of kb's run
        float tb = sb + ((lane < 63 && nkl == kb) ? nv : 0.f);
        atomicAdd(acc + kb, __float2int_rn(tb * SCALE_F));
    }
}

// ---------------------------------------------------------------------------
// out[b] = bias[gix[b % gene_n]] + acc[b] * 2^-20, in place (each thread
// reads its own 4 slots as int4 then overwrites as float4; no cross-thread
// hazard). gene_n divisible by 4 -> g..g+3 never wrap within a quad.
// ---------------------------------------------------------------------------
__global__ __launch_bounds__(256) void finish_kernel(
        float* out, const float* __restrict__ bias,
        const int* __restrict__ gix, int gene_n, int total) {
    int b = (blockIdx.x * blockDim.x + threadIdx.x) * 4;
    if ((gene_n & 3) == 0 && b + 3 < total) {
        int4 a = *(const int4*)((const int*)out + b);
        int g = b % gene_n;
        float4 r;
        r.x = bias[gix[g]]     + (float)a.x * INV_SCALE;
        r.y = bias[gix[g + 1]] + (float)a.y * INV_SCALE;
        r.z = bias[gix[g + 2]] + (float)a.z * INV_SCALE;
        r.w = bias[gix[g + 3]] + (float)a.w * INV_SCALE;
        *(float4*)(out + b) = r;
    } else {
        for (int k = 0; k < 4; ++k) {
            int j = b + k;
            if (j < total) {
                int aj = ((const int*)out)[j];
                out[j] = bias[gix[j % gene_n]] + (float)aj * INV_SCALE;
            }
        }
    }
}

extern "C" void kernel_launch(void* const* d_in, const int* in_sizes, int n_in,
                              void* d_out, int out_size, void* d_ws, size_t ws_size,
                              hipStream_t stream) {
    const float* coords  = (const float*)d_in[0];
    const int*   ix      = (const int*)d_in[1];
    const int*   gene_ix = (const int*)d_in[4];
    const float* freqs   = (const float*)d_in[5];
    const float* weight  = (const float*)d_in[7];
    const float* bias    = (const float*)d_in[8];
    float* out = (float*)d_out;

    int F      = in_sizes[1];
    int gene_n = in_sizes[4];
    int total  = out_size;

    (void)d_ws; (void)ws_size; (void)n_in;

    int zthreads = (total + 3) / 4;
    hipLaunchKernelGGL(init_kernel, dim3((zthreads + 255) / 256), dim3(256),
                       0, stream, (int*)out, total, freqs, weight);

    int blocks = (F + TPB * 2 - 1) / (TPB * 2);
    hipLaunchKernelGGL(scan_kernel, dim3(blocks), dim3(TPB), 0, stream,
                       coords, ix, (int*)out, F);

    hipLaunchKernelGGL(finish_kernel, dim3((zthreads + 255) / 256), dim3(256),
                       0, stream, out, bias, gene_ix, gene_n, total);
}